// Round 3
// baseline (39.358 us; speedup 1.0000x reference)
//
#include <hip/hip_runtime.h>
#include <hip/hip_bf16.h>

// out[q] = min(|{r : dist(q,r) <= thr}|, 100) / 100   (top-k is unnecessary:
// any distance <= thr is among the 100 smallest unless count > 100, which clamps)
//
// Q=4096, R=16384, D=128. hit  <=>  dot(q,r) >= 0.5*|q|^2 + 0.5*(|r|^2 - thr^2)
// dot via bf16 MFMA; margin vs bf16 rounding is ~100 (sq_dist ~ 120..400 vs 0.25).

#define DIM   128
#define ROWB  256              // bytes per bf16 row
#define BM    128
#define BN    64
#define NSPLIT 16              // blocks along R

typedef __attribute__((ext_vector_type(8))) short short8;
typedef __attribute__((ext_vector_type(4))) float f32x4;

#define VMCNT(n) asm volatile("s_waitcnt vmcnt(" #n ")" ::: "memory")

// ---------------- prep: fp32 -> bf16, row norms, zero counts ----------------
__global__ void prep_kernel(const float* __restrict__ qe, const float* __restrict__ re,
                            __hip_bfloat16* __restrict__ qb, __hip_bfloat16* __restrict__ rb,
                            float* __restrict__ qsq, float* __restrict__ rsq,
                            float* __restrict__ counts, int Q, int R) {
    const int wave = threadIdx.x >> 6;
    const int lane = threadIdx.x & 63;
    const int row = blockIdx.x * 4 + wave;
    if (row >= Q + R) return;
    const float* src;
    __hip_bfloat16* dst;
    float* nrm;
    if (row < Q) {
        src = qe + (size_t)row * DIM;
        dst = qb + (size_t)row * DIM;
        nrm = qsq + row;
        if (lane == 0) counts[row] = 0.0f;
    } else {
        int r = row - Q;
        src = re + (size_t)r * DIM;
        dst = rb + (size_t)r * DIM;
        nrm = rsq + r;
    }
    float2 v = ((const float2*)src)[lane];
    float s = v.x * v.x + v.y * v.y;
    __hip_bfloat162 b;
    b.x = __float2bfloat16(v.x);
    b.y = __float2bfloat16(v.y);
    ((__hip_bfloat162*)dst)[lane] = b;
    #pragma unroll
    for (int off = 32; off > 0; off >>= 1) s += __shfl_down(s, off);
    if (lane == 0) *nrm = s;
}

// ---------------- main: A-in-registers, B 4-deep LDS pipeline ----------------
__launch_bounds__(256, 2)
__global__ void dist_count_kernel(const __hip_bfloat16* __restrict__ qb,
                                  const __hip_bfloat16* __restrict__ rb,
                                  const float* __restrict__ qsq,
                                  const float* __restrict__ rsq,
                                  const float* __restrict__ thr_p,
                                  float* __restrict__ counts,
                                  int Q, int R) {
    __shared__ short Bs[4][BN * DIM];      // 4 x 16KB = 64KB

    const int tid  = threadIdx.x;
    const int lane = tid & 63;
    const int wave = tid >> 6;

    const int seg = R / NSPLIT;
    const int nsplit_base = blockIdx.x * seg;
    const int tileM = blockIdx.y;
    const int NT = seg / BN;               // 16 for R=16384

    const int wrow = (wave >> 1) * 64;     // query sub-rows
    const int wcol = (wave & 1) * 32;      // ref sub-cols within tile
    const int lr = lane & 15;
    const int lk = lane >> 4;

    const char* qbc = (const char*)qb;
    const char* rbc = (const char*)rb;

    // stage one 64x128 bf16 tile (16KB): linear LDS dest (wave-uniform base +
    // lane*16, required by global_load_lds), XOR-swizzle applied to the GLOBAL
    // source column; ds_read applies the same XOR (rule #21).
    auto stage = [&](int tile, short* buf) {
        const int ref0 = nsplit_base + tile * BN;
        #pragma unroll
        for (int i = 0; i < 4; ++i) {
            const int chunk = wave * 4 + i;            // 0..15
            const int lds_byte = chunk * 1024 + lane * 16;
            const int row = lds_byte >> 8;             // 0..63
            const int col = lds_byte & 255;
            const int src_col = col ^ ((row & 7) << 4);
            const char* src = rbc + (size_t)(ref0 + row) * ROWB + src_col;
            __builtin_amdgcn_global_load_lds(
                (const __attribute__((address_space(1))) unsigned int*)src,
                (__attribute__((address_space(3))) unsigned int*)((char*)buf + lds_byte),
                16, 0, 0);
        }
    };

    // ---- A fragments for full K=128 in registers (once per block) ----
    short8 a[4][4];                        // [ks][mi]
    #pragma unroll
    for (int ks = 0; ks < 4; ++ks)
        #pragma unroll
        for (int mi = 0; mi < 4; ++mi) {
            const int qrow = tileM * BM + wrow + mi * 16 + lr;
            a[ks][mi] = *(const short8*)(qbc + (size_t)qrow * ROWB + ks * 64 + lk * 16);
        }

    const float thr = *thr_p;
    const float t2 = thr * thr;
    const bool thr_ok = (thr >= 0.0f);

    // 0.5*|q|^2 for this lane's 16 output rows
    float qh[16];
    #pragma unroll
    for (int mi = 0; mi < 4; ++mi)
        #pragma unroll
        for (int reg = 0; reg < 4; ++reg)
            qh[mi * 4 + reg] = 0.5f * qsq[tileM * BM + wrow + mi * 16 + lk * 4 + reg];

    float c[16];
    #pragma unroll
    for (int i = 0; i < 16; ++i) c[i] = 0.0f;

    // per-round body: ds_read B frags + MFMA + threshold-count
    auto body = [&](int t) {
        const char* cur = (const char*)Bs[t & 3];
        f32x4 acc[4][2] = {};
        __builtin_amdgcn_s_setprio(1);
        #pragma unroll
        for (int ks = 0; ks < 4; ++ks) {
            short8 b[2];
            #pragma unroll
            for (int ni = 0; ni < 2; ++ni) {
                const int brow = wcol + ni * 16 + lr;
                const int cb = (ks * 64 + lk * 16) ^ ((brow & 7) << 4);
                b[ni] = *(const short8*)(cur + brow * ROWB + cb);
            }
            #pragma unroll
            for (int mi = 0; mi < 4; ++mi)
                #pragma unroll
                for (int ni = 0; ni < 2; ++ni)
                    acc[mi][ni] = __builtin_amdgcn_mfma_f32_16x16x32_bf16(a[ks][mi], b[ni], acc[mi][ni], 0, 0, 0);
        }
        __builtin_amdgcn_s_setprio(0);

        const int col0 = nsplit_base + t * BN + wcol;
        float rh[2];
        #pragma unroll
        for (int ni = 0; ni < 2; ++ni) {
            const float rv = rsq[col0 + ni * 16 + lr];
            rh[ni] = thr_ok ? 0.5f * (rv - t2) : 1e30f;
        }
        #pragma unroll
        for (int mi = 0; mi < 4; ++mi)
            #pragma unroll
            for (int reg = 0; reg < 4; ++reg) {
                #pragma unroll
                for (int ni = 0; ni < 2; ++ni)
                    if (acc[mi][ni][reg] >= qh[mi * 4 + reg] + rh[ni])
                        c[mi * 4 + reg] += 1.0f;
            }
    };

    // ---- prologue: stage tiles 0..2 ----
    #pragma unroll
    for (int p = 0; p < 3; ++p)
        if (p < NT) stage(p, Bs[p & 3]);

    // ---- main loop: counted vmcnt, never drained to 0 ----
    int t = 0;
    for (; t + 2 < NT; ++t) {
        VMCNT(8);                              // tile t's 4 loads done; t+1,t+2 in flight
        __builtin_amdgcn_s_barrier();
        __builtin_amdgcn_sched_barrier(0);
        if (t + 3 < NT) stage(t + 3, Bs[(t + 3) & 3]);
        body(t);
    }
    if (t < NT) {                              // second-to-last tile
        if (NT >= 2) { VMCNT(4); } else { VMCNT(0); }
        __builtin_amdgcn_s_barrier();
        __builtin_amdgcn_sched_barrier(0);
        body(t);
        ++t;
    }
    if (t < NT) {                              // last tile
        VMCNT(0);
        __builtin_amdgcn_s_barrier();
        __builtin_amdgcn_sched_barrier(0);
        body(t);
    }

    // ---- reduce 16 column-lanes, atomic only if nonzero ----
    #pragma unroll
    for (int mi = 0; mi < 4; ++mi)
        #pragma unroll
        for (int reg = 0; reg < 4; ++reg) {
            float v = c[mi * 4 + reg];
            v += __shfl_xor(v, 1);
            v += __shfl_xor(v, 2);
            v += __shfl_xor(v, 4);
            v += __shfl_xor(v, 8);
            if (lr == 0 && v != 0.0f) {
                const int row = tileM * BM + wrow + mi * 16 + lk * 4 + reg;
                atomicAdd(&counts[row], v);
            }
        }
}

// ---------------- finalize ----------------
__global__ void finalize_kernel(const float* __restrict__ counts,
                                float* __restrict__ out, int Q, int R) {
    int q = blockIdx.x * blockDim.x + threadIdx.x;
    if (q < Q) {
        float k = (R < 100) ? (float)R : 100.0f;
        out[q] = fminf(counts[q], k) / k;
    }
}

extern "C" void kernel_launch(void* const* d_in, const int* in_sizes, int n_in,
                              void* d_out, int out_size, void* d_ws, size_t ws_size,
                              hipStream_t stream) {
    const float* qe  = (const float*)d_in[0];
    const float* re  = (const float*)d_in[1];
    const float* thr = (const float*)d_in[2];
    float* out = (float*)d_out;

    const int Q = in_sizes[0] / DIM;   // 4096
    const int R = in_sizes[1] / DIM;   // 16384

    char* ws = (char*)d_ws;
    __hip_bfloat16* qb = (__hip_bfloat16*)ws;
    __hip_bfloat16* rb = (__hip_bfloat16*)(ws + (size_t)Q * DIM * 2);
    float* qsq    = (float*)(ws + (size_t)(Q + R) * DIM * 2);
    float* rsq    = qsq + Q;
    float* counts = rsq + R;

    const int rows = Q + R;
    prep_kernel<<<(rows + 3) / 4, 256, 0, stream>>>(qe, re, qb, rb, qsq, rsq, counts, Q, R);

    dim3 grid(NSPLIT, Q / BM);   // (16, 32) = 512 blocks = 2/CU
    dist_count_kernel<<<grid, 256, 0, stream>>>(qb, rb, qsq, rsq, thr, counts, Q, R);

    finalize_kernel<<<(Q + 255) / 256, 256, 0, stream>>>(counts, out, Q, R);
}